// Round 5
// baseline (848.848 us; speedup 1.0000x reference)
//
#include <hip/hip_runtime.h>
#include <hip/hip_fp16.h>
#include <math.h>

// Problem constants: F_IN=64, K=16, C=20, L=4, H1=20, H2=2
// N=100k nodes, E=1.6M undirected edges, M=2E=3.2M directed entries.
//
// Incidence structure is built as a true CSR via bucketed counting sort
// (all coalesced writes) instead of random slotted atomics: random sub-line
// write ops cap at ~20 G/s device-wide (measured R1/R4), which made the old
// fill a 320 us floor.

#define SHIFT   7
#define NB_MAX  1024
#define CHUNKB  6144
#define CCAP    5632

// ---------------- K1: filter nets (analytic conv) + bucket histogram -----------
__global__ __launch_bounds__(256) void filter_hist_kernel(
    const float* __restrict__ attr, const float* __restrict__ cutoffs,
    const float* __restrict__ cw1, const float* __restrict__ cb1,
    const float* __restrict__ f1w1, const float* __restrict__ f1b1,
    const float* __restrict__ f2w1, const float* __restrict__ f2b1,
    const float* __restrict__ cw2, const float* __restrict__ cb2,
    const float* __restrict__ f1w2, const float* __restrict__ f1b2,
    const float* __restrict__ f2w2, const float* __restrict__ f2b2,
    const int* __restrict__ ei, int* __restrict__ bucket_cnt,
    float* __restrict__ wedge1, float* __restrict__ wedge2, int E, int NB)
{
    __shared__ float s_cut[16];
    __shared__ float s_w[2][344]; // cw(120) cb(20) f1w(160) f1b(8) f2w(32) f2b(4)
    __shared__ float tab[2 * 20 * 64];
    __shared__ int s_hist[NB_MAX];
    int tid = threadIdx.x;
    if (tid < 16) s_cut[tid] = cutoffs[tid];
    for (int i = tid; i < 344; i += 256) {
        float v1, v2;
        if (i < 120)      { v1 = cw1[i];       v2 = cw2[i]; }
        else if (i < 140) { v1 = cb1[i-120];   v2 = cb2[i-120]; }
        else if (i < 300) { v1 = f1w1[i-140];  v2 = f1w2[i-140]; }
        else if (i < 308) { v1 = f1b1[i-300];  v2 = f1b2[i-300]; }
        else if (i < 340) { v1 = f2w1[i-308];  v2 = f2w2[i-308]; }
        else              { v1 = f2b1[i-340];  v2 = f2b2[i-340]; }
        s_w[0][i] = v1; s_w[1][i] = v2;
    }
    for (int i = tid; i < NB_MAX; i += 256) s_hist[i] = 0;
    __syncthreads();
    if (tid < 40) {
        int l = tid / 20, ch = tid % 20;
        const float* W = s_w[l];
        float w00 = W[ch*6+0], w01 = W[ch*6+1], w02 = W[ch*6+2];
        float w10 = W[ch*6+3], w11 = W[ch*6+4], w12 = W[ch*6+5];
        float b = W[120 + ch];
        float* tb = &tab[(l*20 + ch) * 64];
        tb[0]  = w01*s_cut[0]  + w02*s_cut[1];
        for (int k = 1; k <= 14; ++k)
            tb[k] = w00*s_cut[k-1] + w01*s_cut[k] + w02*s_cut[k+1];
        tb[15] = w00*s_cut[14] + w01*s_cut[15];
        float pm = tb[1]; tb[16+1] = pm;
        for (int j = 2; j <= 14; ++j) { pm = fminf(pm, tb[j]); tb[16+j] = pm; }
        float qm = tb[14]; tb[32+14] = qm;
        for (int j = 13; j >= 1; --j) { qm = fminf(qm, tb[j]); tb[32+j] = qm; }
        tb[48] = w00 + w01 + w02;
        tb[49] = w01 + w02;
        tb[50] = w00 + w01;
        tb[51] = w10 + w11 + w12;
        tb[52] = w10 + w11;
        tb[53] = w10;
        tb[54] = w11;
        tb[55] = w12;
        tb[56] = b;
    }
    __syncthreads();

    for (int e = blockIdx.x * 256 + tid; e < E; e += gridDim.x * 256) {
        int s = ei[e], d = ei[E + e];
        atomicAdd(&s_hist[d >> SHIFT], 1);
        atomicAdd(&s_hist[s >> SHIFT], 1);

        float a = attr[e];
        int idx = 0;
        #pragma unroll
        for (int k = 0; k < 16; ++k) idx += (a > s_cut[k]) ? 1 : 0;

        #pragma unroll
        for (int layer = 0; layer < 2; ++layer) {
            const float* W = s_w[layer];
            float h[20];
            #pragma unroll
            for (int c = 0; c < 20; ++c) {
                const float* tb = &tab[(layer*20 + c) * 64];
                float b = tb[56];
                float base = fmaf(tb[48], a, b);
                float y0 = fmaf(tb[49], a, b) - tb[0];
                y0 += (idx >= 1 ? tb[54] : 0.f) + (idx >= 2 ? tb[55] : 0.f);
                float m = y0;
                float y15 = fmaf(tb[50], a, b) - tb[15];
                y15 += (idx >= 15 ? tb[53] : 0.f) + (idx >= 16 ? tb[54] : 0.f);
                m = fmaxf(m, y15);
                {
                    int j = idx - 2; j = j > 14 ? 14 : j;
                    float v = base + tb[51] - tb[16 + j];
                    m = (idx >= 3) ? fmaxf(m, v) : m;
                }
                {
                    float v = base + tb[52] - tb[(idx >= 2 && idx <= 15) ? (idx-1) : 1];
                    m = (idx >= 2 && idx <= 15) ? fmaxf(m, v) : m;
                }
                {
                    float v = base + tb[53] - tb[(idx >= 1 && idx <= 14) ? idx : 1];
                    m = (idx >= 1 && idx <= 14) ? fmaxf(m, v) : m;
                }
                {
                    int j = idx + 1; j = j < 1 ? 1 : j;
                    float v = base - tb[32 + (j > 14 ? 14 : j)];
                    m = (idx <= 13) ? fmaxf(m, v) : m;
                }
                h[c] = fmaxf(m, 0.f);
            }
            float g[8];
            #pragma unroll
            for (int j = 0; j < 8; ++j) {
                float t = W[300 + j];
                #pragma unroll
                for (int c = 0; c < 20; ++c) t += W[140 + j*20 + c] * h[c];
                g[j] = fmaxf(t, 0.f);
            }
            float4 wo;
            float* wp = (float*)&wo;
            #pragma unroll
            for (int l = 0; l < 4; ++l) {
                float t = W[340 + l];
                #pragma unroll
                for (int j = 0; j < 8; ++j) t += W[308 + l*8 + j] * g[j];
                wp[l] = fmaxf(t, 0.f);
            }
            float4* dstp = (float4*)(layer == 0 ? wedge1 : wedge2);
            dstp[e] = wo;
        }
    }
    __syncthreads();
    for (int i = tid; i < NB; i += 256) {
        int v = s_hist[i];
        if (v) atomicAdd(&bucket_cnt[i], v);
    }
}

// ---------------- K2: exclusive scan of bucket counts (one block) ---------------
__global__ __launch_bounds__(1024) void scan_kernel(
    const int* __restrict__ bcnt, int* __restrict__ bbase, int* __restrict__ bcur,
    int* __restrict__ csr_off, int NB, int M, int N)
{
    __shared__ int s[1024];
    int t = threadIdx.x;
    s[t] = (t < NB) ? bcnt[t] : 0;
    __syncthreads();
    for (int off = 1; off < 1024; off <<= 1) {
        int v = (t >= off) ? s[t - off] : 0;
        __syncthreads();
        s[t] += v;
        __syncthreads();
    }
    int excl = (t == 0) ? 0 : s[t - 1];
    if (t < NB) { bbase[t] = excl; bcur[t] = excl; }
    if (t == 0) { bbase[NB] = M; csr_off[N] = M; }
}

// ---------------- K3: scatter directed entries into bucket-major tmp ------------
// entry.x = nbr node; entry.y = edge-id | (own&127)<<22
__global__ __launch_bounds__(256) void passB_kernel(
    const int* __restrict__ ei, int* __restrict__ bcur, uint2* __restrict__ tmp,
    int E, int M, int NB)
{
    __shared__ int hist[NB_MAX];
    __shared__ int lbase[NB_MAX];
    __shared__ int gpos[NB_MAX];
    __shared__ int aux[256];
    __shared__ uint2 stage[CHUNKB];
    int tid = threadIdx.x;
    int start = blockIdx.x * CHUNKB;
    if (start >= M) return;
    int cnt = M - start; if (cnt > CHUNKB) cnt = CHUNKB;
    for (int i = tid; i < NB_MAX; i += 256) hist[i] = 0;
    __syncthreads();
    for (int i = tid; i < cnt; i += 256) {
        int de = start + i;
        int own = ei[de < E ? de + E : de - E];
        atomicAdd(&hist[own >> SHIFT], 1);
    }
    __syncthreads();
    {   // exclusive scan hist[0..1023] -> lbase, 256 threads x 4 items
        int t4 = tid * 4;
        int a0 = hist[t4], a1 = hist[t4+1], a2 = hist[t4+2], a3 = hist[t4+3];
        aux[tid] = a0 + a1 + a2 + a3;
        __syncthreads();
        for (int off = 1; off < 256; off <<= 1) {
            int v = (tid >= off) ? aux[tid - off] : 0;
            __syncthreads();
            aux[tid] += v;
            __syncthreads();
        }
        int te = (tid == 0) ? 0 : aux[tid - 1];
        lbase[t4]   = te;
        lbase[t4+1] = te + a0;
        lbase[t4+2] = te + a0 + a1;
        lbase[t4+3] = te + a0 + a1 + a2;
    }
    __syncthreads();
    for (int b = tid; b < NB; b += 256) {
        int cb = hist[b];
        gpos[b] = cb ? atomicAdd(&bcur[b], cb) : 0;
    }
    __syncthreads();
    for (int i = tid; i < NB_MAX; i += 256) hist[i] = 0;  // reuse as cursor
    __syncthreads();
    for (int i = tid; i < cnt; i += 256) {
        int de = start + i;
        int j = de < E ? de : de - E;
        int own = ei[de < E ? de + E : de - E];
        unsigned nbr = (unsigned)ei[de];
        int b = own >> SHIFT;
        int p = atomicAdd(&hist[b], 1);
        stage[lbase[b] + p] = make_uint2(nbr, (unsigned)j | ((unsigned)(own & 127) << 22));
    }
    __syncthreads();
    int wave = tid >> 6, lane = tid & 63;
    for (int b = wave; b < NB; b += 4) {
        int n_b = hist[b];
        if (!n_b) continue;
        int lo = lbase[b], g = gpos[b];
        for (int k = lane; k < n_b; k += 64) tmp[(size_t)g + k] = stage[lo + k];
    }
}

// ---------------- K4: per-bucket node sort -> final CSR + offsets ---------------
__global__ __launch_bounds__(256) void passC_kernel(
    const uint2* __restrict__ tmp, const int* __restrict__ bbase,
    uint2* __restrict__ fin, int* __restrict__ csr_off, int NB, int N)
{
    __shared__ uint2 ordered[CCAP];
    __shared__ int hist[128], nexcl[128], cur[128], s2[128];
    int tid = threadIdx.x;
    int b = blockIdx.x;
    int lo = bbase[b], hi = bbase[b + 1];
    int full = hi - lo;
    int cnt = full > CCAP ? CCAP : full;  // overflow guard (statistically never)
    if (tid < 128) hist[tid] = 0;
    __syncthreads();
    for (int i = tid; i < cnt; i += 256)
        atomicAdd(&hist[(tmp[(size_t)lo + i].y >> 22) & 127], 1);
    __syncthreads();
    if (tid < 128) s2[tid] = hist[tid];
    __syncthreads();
    for (int off = 1; off < 128; off <<= 1) {
        int v = (tid < 128 && tid >= off) ? s2[tid - off] : 0;
        __syncthreads();
        if (tid < 128) s2[tid] += v;
        __syncthreads();
    }
    if (tid < 128) {
        int excl = s2[tid] - hist[tid];
        nexcl[tid] = excl;
        cur[tid] = 0;
        int node = (b << SHIFT) + tid;
        if (node < N) csr_off[node] = lo + excl;
    }
    __syncthreads();
    for (int i = tid; i < cnt; i += 256) {
        uint2 en = tmp[(size_t)lo + i];
        int ol = (en.y >> 22) & 127;
        int p = atomicAdd(&cur[ol], 1);
        ordered[nexcl[ol] + p] = en;
    }
    __syncthreads();
    for (int i = tid; i < cnt; i += 256) fin[(size_t)lo + i] = ordered[i];
    for (int i = cnt + tid; i < full; i += 256) fin[(size_t)lo + i] = make_uint2(0u, 0u);
}

// ---------------- K5: h1 = x@root1+bias1 ; x_h = fp16(x) ------------------------
__global__ __launch_bounds__(256) void node_prep1b(
    const float* __restrict__ x, const float* __restrict__ root1,
    const float* __restrict__ bias1, float* __restrict__ h1,
    __half* __restrict__ x_h, int N)
{
    __shared__ float r1s[64 * 21];
    __shared__ float sb[20];
    int tid = threadIdx.x;
    for (int i = tid; i < 1280; i += 256) {
        int f = i / 20, h = i % 20;
        r1s[f*21 + h] = root1[i];
    }
    if (tid < 20) sb[tid] = bias1[tid];
    __syncthreads();
    int t = blockIdx.x * 256 + tid;
    int n = t >> 3, q = t & 7;
    if (n >= N) return;
    const float4* xr = (const float4*)(x + (size_t)n*64 + q*8);
    float4 va = xr[0], vb = xr[1];
    float xf[8] = {va.x, va.y, va.z, va.w, vb.x, vb.y, vb.z, vb.w};
    __half hh[8];
    #pragma unroll
    for (int j = 0; j < 8; ++j) hh[j] = __float2half(xf[j]);
    *(uint4*)(x_h + (size_t)n*64 + q*8) = *(const uint4*)hh;
    float p[20];
    #pragma unroll
    for (int h = 0; h < 20; ++h) p[h] = 0.f;
    #pragma unroll
    for (int j = 0; j < 8; ++j) {
        float xv = xf[j];
        int base = (q*8 + j) * 21;
        #pragma unroll
        for (int h = 0; h < 20; ++h) p[h] += xv * r1s[base + h];
    }
    #pragma unroll
    for (int m = 1; m < 8; m <<= 1) {
        #pragma unroll
        for (int h = 0; h < 20; ++h) p[h] += __shfl_xor(p[h], m, 64);
    }
    if (q < 5) {
        float4 o;
        o.x = p[q*4+0] + sb[q*4+0];
        o.y = p[q*4+1] + sb[q*4+1];
        o.z = p[q*4+2] + sb[q*4+2];
        o.w = p[q*4+3] + sb[q*4+3];
        *(float4*)(h1 + (size_t)n*20 + q*4) = o;
    }
}

// ---------------- K6: CSR gather layer 1 + theta1 + fused node_prep2 ------------
__global__ __launch_bounds__(256) void gather1_fused(
    const int* __restrict__ csr_off, const uint2* __restrict__ fin,
    const float4* __restrict__ wedge1,
    const __half* __restrict__ x_h, const float* __restrict__ h1,
    const float* __restrict__ theta1,
    const float* __restrict__ root2, const float* __restrict__ theta2,
    const float* __restrict__ bias2,
    float* __restrict__ o2, float* __restrict__ P2, int N)
{
    __shared__ float th[4 * 64 * 21];
    __shared__ float w2s[200];
    __shared__ float w2b[2];
    int tid = threadIdx.x;
    for (int i = tid; i < 5120; i += 256) {
        int l = i / 1280, f = (i / 20) % 64, h = i % 20;
        th[(l*64 + f)*21 + h] = theta1[i];
    }
    for (int i = tid; i < 200; i += 256) {
        int o = i / 20, h = i % 20;
        float v;
        if (o < 2) v = root2[h*2 + o];
        else { int l = (o-2) >> 1, jj = (o-2) & 1; v = theta2[l*40 + h*2 + jj]; }
        w2s[i] = v;
    }
    if (tid < 2) w2b[tid] = bias2[tid];
    __syncthreads();
    int t = blockIdx.x * 256 + tid;
    int n = t >> 3, q = t & 7;
    if (n >= N) return;
    int start = csr_off[n];
    int c = csr_off[n + 1] - start;
    const uint2* sl = fin + start;
    float acc[4][8];
    #pragma unroll
    for (int l = 0; l < 4; ++l)
        #pragma unroll
        for (int j = 0; j < 8; ++j) acc[l][j] = 0.f;
    int half = (c + 1) >> 1;
    for (int i = 0; i < half; ++i) {
        uint2 e1 = sl[i];
        int has2 = (i + half) < c;
        uint2 e2 = has2 ? sl[i + half] : e1;
        int nbr1 = (int)e1.x, nbr2 = (int)e2.x;
        unsigned we1 = e1.y & 0x3FFFFFu, we2 = e2.y & 0x3FFFFFu;
        float4 w1 = wedge1[we1];
        float4 w2 = wedge1[we2];
        float z = has2 ? 1.f : 0.f;
        w2.x *= z; w2.y *= z; w2.z *= z; w2.w *= z;
        uint4 hx1 = *(const uint4*)(x_h + (size_t)nbr1*64 + q*8);
        uint4 hx2 = *(const uint4*)(x_h + (size_t)nbr2*64 + q*8);
        const __half* hp1 = (const __half*)&hx1;
        const __half* hp2 = (const __half*)&hx2;
        #pragma unroll
        for (int j2 = 0; j2 < 8; ++j2) {
            float xa = __half2float(hp1[j2]);
            float xb = __half2float(hp2[j2]);
            acc[0][j2] += w1.x * xa + w2.x * xb;
            acc[1][j2] += w1.y * xa + w2.y * xb;
            acc[2][j2] += w1.z * xa + w2.z * xb;
            acc[3][j2] += w1.w * xa + w2.w * xb;
        }
    }
    float p[20];
    #pragma unroll
    for (int h = 0; h < 20; ++h) p[h] = 0.f;
    #pragma unroll
    for (int l = 0; l < 4; ++l) {
        #pragma unroll
        for (int j2 = 0; j2 < 8; ++j2) {
            float a = acc[l][j2];
            int base = ((l << 6) + (q << 3) + j2) * 21;
            #pragma unroll
            for (int h = 0; h < 20; ++h) p[h] += a * th[base + h];
        }
    }
    #pragma unroll
    for (int m = 1; m < 8; m <<= 1) {
        #pragma unroll
        for (int h = 0; h < 20; ++h) p[h] += __shfl_xor(p[h], m, 64);
    }
    const float4* hb = (const float4*)(h1 + (size_t)n*20);
    float hv[20];
    #pragma unroll
    for (int qq = 0; qq < 5; ++qq) {
        float4 v = hb[qq];
        hv[qq*4+0] = fmaxf(p[qq*4+0] + v.x, 0.f);
        hv[qq*4+1] = fmaxf(p[qq*4+1] + v.y, 0.f);
        hv[qq*4+2] = fmaxf(p[qq*4+2] + v.z, 0.f);
        hv[qq*4+3] = fmaxf(p[qq*4+3] + v.w, 0.f);
    }
    for (int o = q; o < 10; o += 8) {
        float v = (o < 2) ? w2b[o] : 0.f;
        #pragma unroll
        for (int h = 0; h < 20; ++h) v += hv[h] * w2s[o*20 + h];
        if (o < 2) o2[(size_t)n*2 + o] = v;
        else       P2[(size_t)n*8 + (o - 2)] = v;
    }
}

// ---------------- K7: CSR gather layer 2 (8 lanes/node) + log_softmax -----------
__global__ __launch_bounds__(256) void gather2_lsm_kernel(
    const int* __restrict__ csr_off, const uint2* __restrict__ fin,
    const float4* __restrict__ wedge2,
    const float4* __restrict__ P2, const float* __restrict__ o2,
    float* __restrict__ out, int N)
{
    int t = blockIdx.x * 256 + threadIdx.x;
    int n = t >> 3, r = t & 7;
    if (n >= N) return;
    int start = csr_off[n];
    int c = csr_off[n + 1] - start;
    const uint2* sl = fin + start;
    float o0 = 0.f, o1 = 0.f;
    for (int i = r; i < c; i += 8) {
        uint2 en = sl[i];
        int nbr = (int)en.x;
        unsigned we = en.y & 0x3FFFFFu;
        float4 w = wedge2[we];
        float4 pa = P2[(size_t)nbr*2], pb = P2[(size_t)nbr*2 + 1];
        o0 += w.x*pa.x + w.y*pa.z + w.z*pb.x + w.w*pb.z;
        o1 += w.x*pa.y + w.y*pa.w + w.z*pb.y + w.w*pb.w;
    }
    #pragma unroll
    for (int m = 1; m < 8; m <<= 1) {
        o0 += __shfl_xor(o0, m, 64);
        o1 += __shfl_xor(o1, m, 64);
    }
    if (r == 0) {
        o0 += o2[(size_t)n*2];
        o1 += o2[(size_t)n*2 + 1];
        float mx = fmaxf(o0, o1);
        float lse = mx + logf(expf(o0 - mx) + expf(o1 - mx));
        out[(size_t)n*2]     = o0 - lse;
        out[(size_t)n*2 + 1] = o1 - lse;
    }
}

// ================= Fallback path (atomic scatter, R1-style) =====================
__global__ __launch_bounds__(256) void node_prep1(
    const float* __restrict__ x, const float* __restrict__ root1,
    const float* __restrict__ theta1, const float* __restrict__ bias1,
    float* __restrict__ h1, float* __restrict__ P1, int N)
{
    __shared__ float Ws[64 * 100];
    __shared__ float xs[8 * 64];
    __shared__ float sb[20];
    int tid = threadIdx.x;
    for (int i = tid; i < 6400; i += 256) {
        int f = i / 100, c = i % 100;
        float v;
        if (c < 20) v = root1[f*20 + c];
        else { int l = (c-20)/20, hh = (c-20)%20; v = theta1[l*1280 + f*20 + hh]; }
        Ws[i] = v;
    }
    if (tid < 20) sb[tid] = bias1[tid];
    int nb = blockIdx.x * 8;
    for (int i = tid; i < 512; i += 256) {
        int nl = i >> 6, f = i & 63;
        int n = nb + nl;
        xs[i] = (n < N) ? x[(size_t)n*64 + f] : 0.f;
    }
    __syncthreads();
    for (int i = tid; i < 800; i += 256) {
        int nl = i / 100, c = i % 100;
        int n = nb + nl;
        if (n >= N) continue;
        float acc = 0.f;
        #pragma unroll 16
        for (int f = 0; f < 64; ++f) acc += xs[nl*64 + f] * Ws[f*100 + c];
        if (c < 20) h1[(size_t)n*20 + c] = acc + sb[c];
        else        P1[(size_t)n*80 + (c - 20)] = acc;
    }
}

__global__ __launch_bounds__(256) void edge_scatter1(
    const int* __restrict__ ei, const float4* __restrict__ wedge1,
    const float4* __restrict__ P1, float* __restrict__ h1, int E)
{
    int e = blockIdx.x * 256 + threadIdx.x;
    if (e >= E) return;
    int s = ei[e], d = ei[E + e];
    float4 w = wedge1[e];
    const float4* Ps = P1 + (size_t)s * 20;
    const float4* Pd = P1 + (size_t)d * 20;
    float* Hs = h1 + (size_t)s * 20;
    float* Hd = h1 + (size_t)d * 20;
    #pragma unroll
    for (int q = 0; q < 5; ++q) {
        float4 a0 = Ps[q], a1 = Ps[5+q], a2 = Ps[10+q], a3 = Ps[15+q];
        atomicAdd(Hd + q*4 + 0, w.x*a0.x + w.y*a1.x + w.z*a2.x + w.w*a3.x);
        atomicAdd(Hd + q*4 + 1, w.x*a0.y + w.y*a1.y + w.z*a2.y + w.w*a3.y);
        atomicAdd(Hd + q*4 + 2, w.x*a0.z + w.y*a1.z + w.z*a2.z + w.w*a3.z);
        atomicAdd(Hd + q*4 + 3, w.x*a0.w + w.y*a1.w + w.z*a2.w + w.w*a3.w);
        float4 b0 = Pd[q], b1 = Pd[5+q], b2 = Pd[10+q], b3 = Pd[15+q];
        atomicAdd(Hs + q*4 + 0, w.x*b0.x + w.y*b1.x + w.z*b2.x + w.w*b3.x);
        atomicAdd(Hs + q*4 + 1, w.x*b0.y + w.y*b1.y + w.z*b2.y + w.w*b3.y);
        atomicAdd(Hs + q*4 + 2, w.x*b0.z + w.y*b1.z + w.z*b2.z + w.w*b3.z);
        atomicAdd(Hs + q*4 + 3, w.x*b0.w + w.y*b1.w + w.z*b2.w + w.w*b3.w);
    }
}

__global__ __launch_bounds__(256) void node_prep2(
    const float* __restrict__ h1, const float* __restrict__ root2,
    const float* __restrict__ theta2, const float* __restrict__ bias2,
    float* __restrict__ out2, float* __restrict__ P2, int N)
{
    __shared__ float sr[40], st[160], sb2[2];
    int tid = threadIdx.x;
    if (tid < 40) sr[tid] = root2[tid];
    if (tid >= 64 && tid < 224) st[tid - 64] = theta2[tid - 64];
    if (tid < 2) sb2[tid] = bias2[tid];
    __syncthreads();
    int n = blockIdx.x * 256 + tid;
    if (n >= N) return;
    float hv[20];
    const float4* hp = (const float4*)(h1 + (size_t)n * 20);
    #pragma unroll
    for (int q = 0; q < 5; ++q) {
        float4 v = hp[q];
        hv[q*4+0] = fmaxf(v.x, 0.f);
        hv[q*4+1] = fmaxf(v.y, 0.f);
        hv[q*4+2] = fmaxf(v.z, 0.f);
        hv[q*4+3] = fmaxf(v.w, 0.f);
    }
    float o0 = sb2[0], o1 = sb2[1];
    #pragma unroll
    for (int h = 0; h < 20; ++h) { o0 += hv[h]*sr[h*2]; o1 += hv[h]*sr[h*2+1]; }
    out2[(size_t)n*2 + 0] = o0;
    out2[(size_t)n*2 + 1] = o1;
    #pragma unroll
    for (int l = 0; l < 4; ++l) {
        float p0 = 0.f, p1 = 0.f;
        #pragma unroll
        for (int h = 0; h < 20; ++h) {
            p0 += hv[h]*st[l*40 + h*2];
            p1 += hv[h]*st[l*40 + h*2 + 1];
        }
        P2[(size_t)n*8 + l*2 + 0] = p0;
        P2[(size_t)n*8 + l*2 + 1] = p1;
    }
}

__global__ __launch_bounds__(256) void edge_scatter2(
    const int* __restrict__ ei, const float4* __restrict__ wedge2,
    const float4* __restrict__ P2, float* __restrict__ out2, int E)
{
    int e = blockIdx.x * 256 + threadIdx.x;
    if (e >= E) return;
    int s = ei[e], d = ei[E + e];
    float4 w = wedge2[e];
    float4 pa = P2[(size_t)s*2], pb = P2[(size_t)s*2 + 1];
    float y0 = w.x*pa.x + w.y*pa.z + w.z*pb.x + w.w*pb.z;
    float y1 = w.x*pa.y + w.y*pa.w + w.z*pb.y + w.w*pb.w;
    atomicAdd(out2 + (size_t)d*2 + 0, y0);
    atomicAdd(out2 + (size_t)d*2 + 1, y1);
    float4 qa = P2[(size_t)d*2], qb = P2[(size_t)d*2 + 1];
    float z0 = w.x*qa.x + w.y*qa.z + w.z*qb.x + w.w*qb.z;
    float z1 = w.x*qa.y + w.y*qa.w + w.z*qb.y + w.w*qb.w;
    atomicAdd(out2 + (size_t)s*2 + 0, z0);
    atomicAdd(out2 + (size_t)s*2 + 1, z1);
}

__global__ __launch_bounds__(256) void logsoftmax_k(
    const float* __restrict__ out2, float* __restrict__ out, int N)
{
    int n = blockIdx.x * 256 + threadIdx.x;
    if (n >= N) return;
    float o0 = out2[(size_t)n*2], o1 = out2[(size_t)n*2 + 1];
    float m = fmaxf(o0, o1);
    float lse = m + logf(expf(o0 - m) + expf(o1 - m));
    out[(size_t)n*2]     = o0 - lse;
    out[(size_t)n*2 + 1] = o1 - lse;
}

extern "C" void kernel_launch(void* const* d_in, const int* in_sizes, int n_in,
                              void* d_out, int out_size, void* d_ws, size_t ws_size,
                              hipStream_t stream)
{
    const float* x     = (const float*)d_in[0];
    const int*   ei    = (const int*)d_in[1];
    const float* attr  = (const float*)d_in[2];
    const float* cut   = (const float*)d_in[3];
    const float* cw1   = (const float*)d_in[4];
    const float* cb1   = (const float*)d_in[5];
    const float* f1w1  = (const float*)d_in[6];
    const float* f1b1  = (const float*)d_in[7];
    const float* f2w1  = (const float*)d_in[8];
    const float* f2b1  = (const float*)d_in[9];
    const float* th1   = (const float*)d_in[10];
    const float* rt1   = (const float*)d_in[11];
    const float* bs1   = (const float*)d_in[12];
    const float* cw2   = (const float*)d_in[13];
    const float* cb2   = (const float*)d_in[14];
    const float* f1w2  = (const float*)d_in[15];
    const float* f1b2  = (const float*)d_in[16];
    const float* f2w2  = (const float*)d_in[17];
    const float* f2b2  = (const float*)d_in[18];
    const float* th2   = (const float*)d_in[19];
    const float* rt2   = (const float*)d_in[20];
    const float* bs2   = (const float*)d_in[21];

    const int N = in_sizes[0] / 64;
    const int E = in_sizes[1] / 2;
    const int M = 2 * E;
    const int NB = (N + 127) >> SHIFT;

    // ---- workspace layout (words) ----
    size_t W = 0;
    float* ws = (float*)d_ws;
    float* wedge1 = ws + W;            W += (size_t)E * 4;
    float* wedge2 = ws + W;            W += (size_t)E * 4;
    uint2* fin    = (uint2*)(ws + W);  W += (size_t)M * 2;
    int* csr_off  = (int*)(ws + W);    W += (size_t)N + 1;
    int* bcnt     = (int*)(ws + W);    W += NB;
    int* bbase    = (int*)(ws + W);    W += NB + 1;
    int* bcur     = (int*)(ws + W);    W += NB;
    W = (W + 31) & ~(size_t)31;        // 128B-align region X
    size_t nodeRegion = (size_t)N * 62; // x_h(32N) + h1(20N) + P2(8N) + o2(2N)
    size_t tmpRegion  = (size_t)M * 2;
    size_t regionX = nodeRegion > tmpRegion ? nodeRegion : tmpRegion;
    __half* x_h = (__half*)(ws + W);               // 32N words
    float*  h1  = ws + W + (size_t)N * 32;         // 20N
    float*  P2  = ws + W + (size_t)N * 52;         // 8N
    float*  o2  = ws + W + (size_t)N * 60;         // 2N
    uint2*  tmp = (uint2*)(ws + W);                // aliases x_h/h1/P2/o2 (dead by then)
    size_t need_new = W + regionX;

    bool okNew = (N <= (NB_MAX << SHIFT)) && (E <= 0x3FFFFF) &&
                 (ws_size / 4 >= need_new);

    if (okNew) {
        hipMemsetAsync(bcnt, 0, (size_t)NB * 4, stream);
        filter_hist_kernel<<<512, 256, 0, stream>>>(
            attr, cut, cw1, cb1, f1w1, f1b1, f2w1, f2b1,
            cw2, cb2, f1w2, f1b2, f2w2, f2b2,
            ei, bcnt, wedge1, wedge2, E, NB);
        scan_kernel<<<1, 1024, 0, stream>>>(bcnt, bbase, bcur, csr_off, NB, M, N);
        passB_kernel<<<(M + CHUNKB - 1) / CHUNKB, 256, 0, stream>>>(
            ei, bcur, tmp, E, M, NB);
        passC_kernel<<<NB, 256, 0, stream>>>(tmp, bbase, fin, csr_off, NB, N);
        node_prep1b<<<(N * 8 + 255) / 256, 256, 0, stream>>>(x, rt1, bs1, h1, x_h, N);
        gather1_fused<<<(N * 8 + 255) / 256, 256, 0, stream>>>(
            csr_off, fin, (const float4*)wedge1, x_h, h1,
            th1, rt2, th2, bs2, o2, P2, N);
        gather2_lsm_kernel<<<(N * 8 + 255) / 256, 256, 0, stream>>>(
            csr_off, fin, (const float4*)wedge2, (const float4*)P2, o2,
            (float*)d_out, N);
    } else {
        // Fallback: atomic scatter (correct but slow). Independent layout.
        float* fw1 = ws;                           // 4E
        float* fw2 = fw1 + (size_t)E * 4;          // 4E
        float* P1  = fw2 + (size_t)E * 4;          // 80N
        float* fh1 = P1  + (size_t)N * 80;         // 20N
        float* fP2 = fh1 + (size_t)N * 20;         // 8N
        float* fo2 = fP2 + (size_t)N * 8;          // 2N
        filter_hist_kernel<<<512, 256, 0, stream>>>(
            attr, cut, cw1, cb1, f1w1, f1b1, f2w1, f2b1,
            cw2, cb2, f1w2, f1b2, f2w2, f2b2,
            ei, (int*)fo2 /*dummy hist target, overwritten later*/, fw1, fw2, E,
            NB <= NB_MAX ? NB : NB_MAX);
        node_prep1<<<(N + 7) / 8, 256, 0, stream>>>(x, rt1, th1, bs1, fh1, P1, N);
        edge_scatter1<<<(E + 255) / 256, 256, 0, stream>>>(
            ei, (const float4*)fw1, (const float4*)P1, fh1, E);
        node_prep2<<<(N + 255) / 256, 256, 0, stream>>>(fh1, rt2, th2, bs2, fo2, fP2, N);
        edge_scatter2<<<(E + 255) / 256, 256, 0, stream>>>(
            ei, (const float4*)fw2, (const float4*)fP2, fo2, E);
        logsoftmax_k<<<(N + 255) / 256, 256, 0, stream>>>(fo2, (float*)d_out, N);
    }
}

// Round 6
// 632.087 us; speedup vs baseline: 1.3429x; 1.3429x over previous
//
#include <hip/hip_runtime.h>
#include <hip/hip_fp16.h>
#include <math.h>

// Problem constants: F_IN=64, K=16, C=20, L=4, H1=20, H2=2
// N=100k nodes, E=1.6M undirected edges, M=2E=3.2M directed entries.
//
// R5 lesson: fusing the bucket histogram into the filter kernel (grid-stride,
// 512 blocks) blew VGPR to 164 and occupancy to 11% -> latency-bound 350us.
// This round: standalone one-edge-per-thread filter (28 VGPR, 84% occ in R4),
// and capacity buckets (mean 4096, BCAP=4608=+8sigma) so the histogram+scan
// passes disappear entirely. passC emits per-node (off,deg) over padded
// buckets instead of a contiguous CSR.

#define SHIFT   7
#define NB_MAX  1024
#define CHUNKB  6144
#define BCAP    4608

// ---------------- K1: filter nets (analytic conv), one edge per thread ----------
__global__ __launch_bounds__(256) void filter_kernel(
    const float* __restrict__ attr, const float* __restrict__ cutoffs,
    const float* __restrict__ cw1, const float* __restrict__ cb1,
    const float* __restrict__ f1w1, const float* __restrict__ f1b1,
    const float* __restrict__ f2w1, const float* __restrict__ f2b1,
    const float* __restrict__ cw2, const float* __restrict__ cb2,
    const float* __restrict__ f1w2, const float* __restrict__ f1b2,
    const float* __restrict__ f2w2, const float* __restrict__ f2b2,
    float* __restrict__ wedge1, float* __restrict__ wedge2, int E)
{
    __shared__ float s_cut[16];
    __shared__ float s_w[2][344]; // cw(120) cb(20) f1w(160) f1b(8) f2w(32) f2b(4)
    __shared__ float tab[2 * 20 * 64];
    int tid = threadIdx.x;
    if (tid < 16) s_cut[tid] = cutoffs[tid];
    for (int i = tid; i < 344; i += 256) {
        float v1, v2;
        if (i < 120)      { v1 = cw1[i];       v2 = cw2[i]; }
        else if (i < 140) { v1 = cb1[i-120];   v2 = cb2[i-120]; }
        else if (i < 300) { v1 = f1w1[i-140];  v2 = f1w2[i-140]; }
        else if (i < 308) { v1 = f1b1[i-300];  v2 = f1b2[i-300]; }
        else if (i < 340) { v1 = f2w1[i-308];  v2 = f2w2[i-308]; }
        else              { v1 = f2b1[i-340];  v2 = f2b2[i-340]; }
        s_w[0][i] = v1; s_w[1][i] = v2;
    }
    __syncthreads();
    if (tid < 40) {
        int l = tid / 20, ch = tid % 20;
        const float* W = s_w[l];
        float w00 = W[ch*6+0], w01 = W[ch*6+1], w02 = W[ch*6+2];
        float w10 = W[ch*6+3], w11 = W[ch*6+4], w12 = W[ch*6+5];
        float b = W[120 + ch];
        float* tb = &tab[(l*20 + ch) * 64];
        tb[0]  = w01*s_cut[0]  + w02*s_cut[1];
        for (int k = 1; k <= 14; ++k)
            tb[k] = w00*s_cut[k-1] + w01*s_cut[k] + w02*s_cut[k+1];
        tb[15] = w00*s_cut[14] + w01*s_cut[15];
        float pm = tb[1]; tb[16+1] = pm;
        for (int j = 2; j <= 14; ++j) { pm = fminf(pm, tb[j]); tb[16+j] = pm; }
        float qm = tb[14]; tb[32+14] = qm;
        for (int j = 13; j >= 1; --j) { qm = fminf(qm, tb[j]); tb[32+j] = qm; }
        tb[48] = w00 + w01 + w02;
        tb[49] = w01 + w02;
        tb[50] = w00 + w01;
        tb[51] = w10 + w11 + w12;
        tb[52] = w10 + w11;
        tb[53] = w10;
        tb[54] = w11;
        tb[55] = w12;
        tb[56] = b;
    }
    __syncthreads();
    int e = blockIdx.x * 256 + tid;
    if (e >= E) return;

    float a = attr[e];
    int idx = 0;
    #pragma unroll
    for (int k = 0; k < 16; ++k) idx += (a > s_cut[k]) ? 1 : 0;

    #pragma unroll
    for (int layer = 0; layer < 2; ++layer) {
        const float* W = s_w[layer];
        float h[20];
        #pragma unroll
        for (int c = 0; c < 20; ++c) {
            const float* tb = &tab[(layer*20 + c) * 64];
            float b = tb[56];
            float base = fmaf(tb[48], a, b);
            float y0 = fmaf(tb[49], a, b) - tb[0];
            y0 += (idx >= 1 ? tb[54] : 0.f) + (idx >= 2 ? tb[55] : 0.f);
            float m = y0;
            float y15 = fmaf(tb[50], a, b) - tb[15];
            y15 += (idx >= 15 ? tb[53] : 0.f) + (idx >= 16 ? tb[54] : 0.f);
            m = fmaxf(m, y15);
            {
                int j = idx - 2; j = j > 14 ? 14 : j;
                float v = base + tb[51] - tb[16 + j];
                m = (idx >= 3) ? fmaxf(m, v) : m;
            }
            {
                float v = base + tb[52] - tb[(idx >= 2 && idx <= 15) ? (idx-1) : 1];
                m = (idx >= 2 && idx <= 15) ? fmaxf(m, v) : m;
            }
            {
                float v = base + tb[53] - tb[(idx >= 1 && idx <= 14) ? idx : 1];
                m = (idx >= 1 && idx <= 14) ? fmaxf(m, v) : m;
            }
            {
                int j = idx + 1; j = j < 1 ? 1 : j;
                float v = base - tb[32 + (j > 14 ? 14 : j)];
                m = (idx <= 13) ? fmaxf(m, v) : m;
            }
            h[c] = fmaxf(m, 0.f);
        }
        float g[8];
        #pragma unroll
        for (int j = 0; j < 8; ++j) {
            float t = W[300 + j];
            #pragma unroll
            for (int c = 0; c < 20; ++c) t += W[140 + j*20 + c] * h[c];
            g[j] = fmaxf(t, 0.f);
        }
        float4 wo;
        float* wp = (float*)&wo;
        #pragma unroll
        for (int l = 0; l < 4; ++l) {
            float t = W[340 + l];
            #pragma unroll
            for (int j = 0; j < 8; ++j) t += W[308 + l*8 + j] * g[j];
            wp[l] = fmaxf(t, 0.f);
        }
        float4* dstp = (float4*)(layer == 0 ? wedge1 : wedge2);
        dstp[e] = wo;
    }
}

// ---------------- K2: init bucket cursors to capacity bases ---------------------
__global__ __launch_bounds__(256) void init_bcur_kernel(int* __restrict__ bcur, int NB)
{
    int b = blockIdx.x * 256 + threadIdx.x;
    if (b < NB) bcur[b] = b * BCAP;
}

// ---------------- K3: scatter directed entries into capacity buckets ------------
// entry.x = nbr node; entry.y = edge-id | (own&127)<<22
__global__ __launch_bounds__(256) void passB_kernel(
    const int* __restrict__ ei, int* __restrict__ bcur, uint2* __restrict__ tmp,
    int E, int M, int NB)
{
    __shared__ int hist[NB_MAX];
    __shared__ int lbase[NB_MAX];
    __shared__ int gpos[NB_MAX];
    __shared__ int aux[256];
    __shared__ uint2 stage[CHUNKB];
    int tid = threadIdx.x;
    int start = blockIdx.x * CHUNKB;
    if (start >= M) return;
    int cnt = M - start; if (cnt > CHUNKB) cnt = CHUNKB;
    for (int i = tid; i < NB_MAX; i += 256) hist[i] = 0;
    __syncthreads();
    for (int i = tid; i < cnt; i += 256) {
        int de = start + i;
        int own = ei[de < E ? de + E : de - E];
        atomicAdd(&hist[own >> SHIFT], 1);
    }
    __syncthreads();
    {   // exclusive scan hist[0..1023] -> lbase, 256 threads x 4 items
        int t4 = tid * 4;
        int a0 = hist[t4], a1 = hist[t4+1], a2 = hist[t4+2], a3 = hist[t4+3];
        aux[tid] = a0 + a1 + a2 + a3;
        __syncthreads();
        for (int off = 1; off < 256; off <<= 1) {
            int v = (tid >= off) ? aux[tid - off] : 0;
            __syncthreads();
            aux[tid] += v;
            __syncthreads();
        }
        int te = (tid == 0) ? 0 : aux[tid - 1];
        lbase[t4]   = te;
        lbase[t4+1] = te + a0;
        lbase[t4+2] = te + a0 + a1;
        lbase[t4+3] = te + a0 + a1 + a2;
    }
    __syncthreads();
    for (int b = tid; b < NB; b += 256) {
        int cb = hist[b];
        gpos[b] = cb ? atomicAdd(&bcur[b], cb) : 0;
    }
    __syncthreads();
    for (int i = tid; i < NB_MAX; i += 256) hist[i] = 0;  // reuse as cursor
    __syncthreads();
    for (int i = tid; i < cnt; i += 256) {
        int de = start + i;
        int j = de < E ? de : de - E;
        int own = ei[de < E ? de + E : de - E];
        unsigned nbr = (unsigned)ei[de];
        int b = own >> SHIFT;
        int p = atomicAdd(&hist[b], 1);
        stage[lbase[b] + p] = make_uint2(nbr, (unsigned)j | ((unsigned)(own & 127) << 22));
    }
    __syncthreads();
    int wave = tid >> 6, lane = tid & 63;
    for (int b = wave; b < NB; b += 4) {
        int n_b = hist[b];
        if (!n_b) continue;
        int lo = lbase[b], g = gpos[b];
        int lim = (b + 1) * BCAP;          // capacity guard (statistically never hit)
        for (int k = lane; k < n_b; k += 64) {
            if (g + k < lim) tmp[(size_t)g + k] = stage[lo + k];
        }
    }
}

// ---------------- K4: per-bucket node sort in place -> (off, deg) ---------------
__global__ __launch_bounds__(256) void passC_kernel(
    uint2* __restrict__ tmp, const int* __restrict__ bcur,
    int* __restrict__ off, int* __restrict__ deg, int N)
{
    __shared__ uint2 ordered[BCAP];
    __shared__ int hist[128], nexcl[128], cur[128], s2[128];
    int tid = threadIdx.x;
    int b = blockIdx.x;
    int lo = b * BCAP;
    int cnt = bcur[b] - lo;
    if (cnt > BCAP) cnt = BCAP;
    if (tid < 128) hist[tid] = 0;
    __syncthreads();
    for (int i = tid; i < cnt; i += 256)
        atomicAdd(&hist[(tmp[(size_t)lo + i].y >> 22) & 127], 1);
    __syncthreads();
    if (tid < 128) s2[tid] = hist[tid];
    __syncthreads();
    for (int o = 1; o < 128; o <<= 1) {
        int v = (tid < 128 && tid >= o) ? s2[tid - o] : 0;
        __syncthreads();
        if (tid < 128) s2[tid] += v;
        __syncthreads();
    }
    if (tid < 128) {
        int excl = s2[tid] - hist[tid];
        nexcl[tid] = excl;
        cur[tid] = 0;
        int node = (b << SHIFT) + tid;
        if (node < N) { off[node] = lo + excl; deg[node] = hist[tid]; }
    }
    __syncthreads();
    for (int i = tid; i < cnt; i += 256) {
        uint2 en = tmp[(size_t)lo + i];
        int ol = (en.y >> 22) & 127;
        int p = atomicAdd(&cur[ol], 1);
        ordered[nexcl[ol] + p] = en;
    }
    __syncthreads();
    for (int i = tid; i < cnt; i += 256) tmp[(size_t)lo + i] = ordered[i];
}

// ---------------- K5: h1 = x@root1+bias1 ; x_h = fp16(x) ------------------------
__global__ __launch_bounds__(256) void node_prep1b(
    const float* __restrict__ x, const float* __restrict__ root1,
    const float* __restrict__ bias1, float* __restrict__ h1,
    __half* __restrict__ x_h, int N)
{
    __shared__ float r1s[64 * 21];
    __shared__ float sb[20];
    int tid = threadIdx.x;
    for (int i = tid; i < 1280; i += 256) {
        int f = i / 20, h = i % 20;
        r1s[f*21 + h] = root1[i];
    }
    if (tid < 20) sb[tid] = bias1[tid];
    __syncthreads();
    int t = blockIdx.x * 256 + tid;
    int n = t >> 3, q = t & 7;
    if (n >= N) return;
    const float4* xr = (const float4*)(x + (size_t)n*64 + q*8);
    float4 va = xr[0], vb = xr[1];
    float xf[8] = {va.x, va.y, va.z, va.w, vb.x, vb.y, vb.z, vb.w};
    __half hh[8];
    #pragma unroll
    for (int j = 0; j < 8; ++j) hh[j] = __float2half(xf[j]);
    *(uint4*)(x_h + (size_t)n*64 + q*8) = *(const uint4*)hh;
    float p[20];
    #pragma unroll
    for (int h = 0; h < 20; ++h) p[h] = 0.f;
    #pragma unroll
    for (int j = 0; j < 8; ++j) {
        float xv = xf[j];
        int base = (q*8 + j) * 21;
        #pragma unroll
        for (int h = 0; h < 20; ++h) p[h] += xv * r1s[base + h];
    }
    #pragma unroll
    for (int m = 1; m < 8; m <<= 1) {
        #pragma unroll
        for (int h = 0; h < 20; ++h) p[h] += __shfl_xor(p[h], m, 64);
    }
    if (q < 5) {
        float4 o;
        o.x = p[q*4+0] + sb[q*4+0];
        o.y = p[q*4+1] + sb[q*4+1];
        o.z = p[q*4+2] + sb[q*4+2];
        o.w = p[q*4+3] + sb[q*4+3];
        *(float4*)(h1 + (size_t)n*20 + q*4) = o;
    }
}

// ---------------- K6: gather layer 1 + theta1 + fused node_prep2 ----------------
__global__ __launch_bounds__(256) void gather1_fused(
    const int* __restrict__ off, const int* __restrict__ deg,
    const uint2* __restrict__ fin, const float4* __restrict__ wedge1,
    const __half* __restrict__ x_h, const float* __restrict__ h1,
    const float* __restrict__ theta1,
    const float* __restrict__ root2, const float* __restrict__ theta2,
    const float* __restrict__ bias2,
    float* __restrict__ o2, float* __restrict__ P2, int N)
{
    __shared__ float th[4 * 64 * 21];
    __shared__ float w2s[200];
    __shared__ float w2b[2];
    int tid = threadIdx.x;
    for (int i = tid; i < 5120; i += 256) {
        int l = i / 1280, f = (i / 20) % 64, h = i % 20;
        th[(l*64 + f)*21 + h] = theta1[i];
    }
    for (int i = tid; i < 200; i += 256) {
        int o = i / 20, h = i % 20;
        float v;
        if (o < 2) v = root2[h*2 + o];
        else { int l = (o-2) >> 1, jj = (o-2) & 1; v = theta2[l*40 + h*2 + jj]; }
        w2s[i] = v;
    }
    if (tid < 2) w2b[tid] = bias2[tid];
    __syncthreads();
    int t = blockIdx.x * 256 + tid;
    int n = t >> 3, q = t & 7;
    if (n >= N) return;
    int start = off[n];
    int c = deg[n];
    const uint2* sl = fin + start;
    float acc[4][8];
    #pragma unroll
    for (int l = 0; l < 4; ++l)
        #pragma unroll
        for (int j = 0; j < 8; ++j) acc[l][j] = 0.f;
    int half = (c + 1) >> 1;
    for (int i = 0; i < half; ++i) {
        uint2 e1 = sl[i];
        int has2 = (i + half) < c;
        uint2 e2 = has2 ? sl[i + half] : e1;
        int nbr1 = (int)e1.x, nbr2 = (int)e2.x;
        unsigned we1 = e1.y & 0x3FFFFFu, we2 = e2.y & 0x3FFFFFu;
        float4 w1 = wedge1[we1];
        float4 w2 = wedge1[we2];
        float z = has2 ? 1.f : 0.f;
        w2.x *= z; w2.y *= z; w2.z *= z; w2.w *= z;
        uint4 hx1 = *(const uint4*)(x_h + (size_t)nbr1*64 + q*8);
        uint4 hx2 = *(const uint4*)(x_h + (size_t)nbr2*64 + q*8);
        const __half* hp1 = (const __half*)&hx1;
        const __half* hp2 = (const __half*)&hx2;
        #pragma unroll
        for (int j2 = 0; j2 < 8; ++j2) {
            float xa = __half2float(hp1[j2]);
            float xb = __half2float(hp2[j2]);
            acc[0][j2] += w1.x * xa + w2.x * xb;
            acc[1][j2] += w1.y * xa + w2.y * xb;
            acc[2][j2] += w1.z * xa + w2.z * xb;
            acc[3][j2] += w1.w * xa + w2.w * xb;
        }
    }
    float p[20];
    #pragma unroll
    for (int h = 0; h < 20; ++h) p[h] = 0.f;
    #pragma unroll
    for (int l = 0; l < 4; ++l) {
        #pragma unroll
        for (int j2 = 0; j2 < 8; ++j2) {
            float a = acc[l][j2];
            int base = ((l << 6) + (q << 3) + j2) * 21;
            #pragma unroll
            for (int h = 0; h < 20; ++h) p[h] += a * th[base + h];
        }
    }
    #pragma unroll
    for (int m = 1; m < 8; m <<= 1) {
        #pragma unroll
        for (int h = 0; h < 20; ++h) p[h] += __shfl_xor(p[h], m, 64);
    }
    const float4* hb = (const float4*)(h1 + (size_t)n*20);
    float hv[20];
    #pragma unroll
    for (int qq = 0; qq < 5; ++qq) {
        float4 v = hb[qq];
        hv[qq*4+0] = fmaxf(p[qq*4+0] + v.x, 0.f);
        hv[qq*4+1] = fmaxf(p[qq*4+1] + v.y, 0.f);
        hv[qq*4+2] = fmaxf(p[qq*4+2] + v.z, 0.f);
        hv[qq*4+3] = fmaxf(p[qq*4+3] + v.w, 0.f);
    }
    for (int o = q; o < 10; o += 8) {
        float v = (o < 2) ? w2b[o] : 0.f;
        #pragma unroll
        for (int h = 0; h < 20; ++h) v += hv[h] * w2s[o*20 + h];
        if (o < 2) o2[(size_t)n*2 + o] = v;
        else       P2[(size_t)n*8 + (o - 2)] = v;
    }
}

// ---------------- K7: gather layer 2 (8 lanes/node) + log_softmax ---------------
__global__ __launch_bounds__(256) void gather2_lsm_kernel(
    const int* __restrict__ off, const int* __restrict__ deg,
    const uint2* __restrict__ fin, const float4* __restrict__ wedge2,
    const float4* __restrict__ P2, const float* __restrict__ o2,
    float* __restrict__ out, int N)
{
    int t = blockIdx.x * 256 + threadIdx.x;
    int n = t >> 3, r = t & 7;
    if (n >= N) return;
    int start = off[n];
    int c = deg[n];
    const uint2* sl = fin + start;
    float o0 = 0.f, o1 = 0.f;
    for (int i = r; i < c; i += 8) {
        uint2 en = sl[i];
        int nbr = (int)en.x;
        unsigned we = en.y & 0x3FFFFFu;
        float4 w = wedge2[we];
        float4 pa = P2[(size_t)nbr*2], pb = P2[(size_t)nbr*2 + 1];
        o0 += w.x*pa.x + w.y*pa.z + w.z*pb.x + w.w*pb.z;
        o1 += w.x*pa.y + w.y*pa.w + w.z*pb.y + w.w*pb.w;
    }
    #pragma unroll
    for (int m = 1; m < 8; m <<= 1) {
        o0 += __shfl_xor(o0, m, 64);
        o1 += __shfl_xor(o1, m, 64);
    }
    if (r == 0) {
        o0 += o2[(size_t)n*2];
        o1 += o2[(size_t)n*2 + 1];
        float mx = fmaxf(o0, o1);
        float lse = mx + logf(expf(o0 - mx) + expf(o1 - mx));
        out[(size_t)n*2]     = o0 - lse;
        out[(size_t)n*2 + 1] = o1 - lse;
    }
}

// ================= Fallback path (atomic scatter, R1-style) =====================
__global__ __launch_bounds__(256) void node_prep1(
    const float* __restrict__ x, const float* __restrict__ root1,
    const float* __restrict__ theta1, const float* __restrict__ bias1,
    float* __restrict__ h1, float* __restrict__ P1, int N)
{
    __shared__ float Ws[64 * 100];
    __shared__ float xs[8 * 64];
    __shared__ float sb[20];
    int tid = threadIdx.x;
    for (int i = tid; i < 6400; i += 256) {
        int f = i / 100, c = i % 100;
        float v;
        if (c < 20) v = root1[f*20 + c];
        else { int l = (c-20)/20, hh = (c-20)%20; v = theta1[l*1280 + f*20 + hh]; }
        Ws[i] = v;
    }
    if (tid < 20) sb[tid] = bias1[tid];
    int nb = blockIdx.x * 8;
    for (int i = tid; i < 512; i += 256) {
        int nl = i >> 6, f = i & 63;
        int n = nb + nl;
        xs[i] = (n < N) ? x[(size_t)n*64 + f] : 0.f;
    }
    __syncthreads();
    for (int i = tid; i < 800; i += 256) {
        int nl = i / 100, c = i % 100;
        int n = nb + nl;
        if (n >= N) continue;
        float acc = 0.f;
        #pragma unroll 16
        for (int f = 0; f < 64; ++f) acc += xs[nl*64 + f] * Ws[f*100 + c];
        if (c < 20) h1[(size_t)n*20 + c] = acc + sb[c];
        else        P1[(size_t)n*80 + (c - 20)] = acc;
    }
}

__global__ __launch_bounds__(256) void edge_scatter1(
    const int* __restrict__ ei, const float4* __restrict__ wedge1,
    const float4* __restrict__ P1, float* __restrict__ h1, int E)
{
    int e = blockIdx.x * 256 + threadIdx.x;
    if (e >= E) return;
    int s = ei[e], d = ei[E + e];
    float4 w = wedge1[e];
    const float4* Ps = P1 + (size_t)s * 20;
    const float4* Pd = P1 + (size_t)d * 20;
    float* Hs = h1 + (size_t)s * 20;
    float* Hd = h1 + (size_t)d * 20;
    #pragma unroll
    for (int q = 0; q < 5; ++q) {
        float4 a0 = Ps[q], a1 = Ps[5+q], a2 = Ps[10+q], a3 = Ps[15+q];
        atomicAdd(Hd + q*4 + 0, w.x*a0.x + w.y*a1.x + w.z*a2.x + w.w*a3.x);
        atomicAdd(Hd + q*4 + 1, w.x*a0.y + w.y*a1.y + w.z*a2.y + w.w*a3.y);
        atomicAdd(Hd + q*4 + 2, w.x*a0.z + w.y*a1.z + w.z*a2.z + w.w*a3.z);
        atomicAdd(Hd + q*4 + 3, w.x*a0.w + w.y*a1.w + w.z*a2.w + w.w*a3.w);
        float4 b0 = Pd[q], b1 = Pd[5+q], b2 = Pd[10+q], b3 = Pd[15+q];
        atomicAdd(Hs + q*4 + 0, w.x*b0.x + w.y*b1.x + w.z*b2.x + w.w*b3.x);
        atomicAdd(Hs + q*4 + 1, w.x*b0.y + w.y*b1.y + w.z*b2.y + w.w*b3.y);
        atomicAdd(Hs + q*4 + 2, w.x*b0.z + w.y*b1.z + w.z*b2.z + w.w*b3.z);
        atomicAdd(Hs + q*4 + 3, w.x*b0.w + w.y*b1.w + w.z*b2.w + w.w*b3.w);
    }
}

__global__ __launch_bounds__(256) void node_prep2(
    const float* __restrict__ h1, const float* __restrict__ root2,
    const float* __restrict__ theta2, const float* __restrict__ bias2,
    float* __restrict__ out2, float* __restrict__ P2, int N)
{
    __shared__ float sr[40], st[160], sb2[2];
    int tid = threadIdx.x;
    if (tid < 40) sr[tid] = root2[tid];
    if (tid >= 64 && tid < 224) st[tid - 64] = theta2[tid - 64];
    if (tid < 2) sb2[tid] = bias2[tid];
    __syncthreads();
    int n = blockIdx.x * 256 + tid;
    if (n >= N) return;
    float hv[20];
    const float4* hp = (const float4*)(h1 + (size_t)n * 20);
    #pragma unroll
    for (int q = 0; q < 5; ++q) {
        float4 v = hp[q];
        hv[q*4+0] = fmaxf(v.x, 0.f);
        hv[q*4+1] = fmaxf(v.y, 0.f);
        hv[q*4+2] = fmaxf(v.z, 0.f);
        hv[q*4+3] = fmaxf(v.w, 0.f);
    }
    float o0 = sb2[0], o1 = sb2[1];
    #pragma unroll
    for (int h = 0; h < 20; ++h) { o0 += hv[h]*sr[h*2]; o1 += hv[h]*sr[h*2+1]; }
    out2[(size_t)n*2 + 0] = o0;
    out2[(size_t)n*2 + 1] = o1;
    #pragma unroll
    for (int l = 0; l < 4; ++l) {
        float p0 = 0.f, p1 = 0.f;
        #pragma unroll
        for (int h = 0; h < 20; ++h) {
            p0 += hv[h]*st[l*40 + h*2];
            p1 += hv[h]*st[l*40 + h*2 + 1];
        }
        P2[(size_t)n*8 + l*2 + 0] = p0;
        P2[(size_t)n*8 + l*2 + 1] = p1;
    }
}

__global__ __launch_bounds__(256) void edge_scatter2(
    const int* __restrict__ ei, const float4* __restrict__ wedge2,
    const float4* __restrict__ P2, float* __restrict__ out2, int E)
{
    int e = blockIdx.x * 256 + threadIdx.x;
    if (e >= E) return;
    int s = ei[e], d = ei[E + e];
    float4 w = wedge2[e];
    float4 pa = P2[(size_t)s*2], pb = P2[(size_t)s*2 + 1];
    float y0 = w.x*pa.x + w.y*pa.z + w.z*pb.x + w.w*pb.z;
    float y1 = w.x*pa.y + w.y*pa.w + w.z*pb.y + w.w*pb.w;
    atomicAdd(out2 + (size_t)d*2 + 0, y0);
    atomicAdd(out2 + (size_t)d*2 + 1, y1);
    float4 qa = P2[(size_t)d*2], qb = P2[(size_t)d*2 + 1];
    float z0 = w.x*qa.x + w.y*qa.z + w.z*qb.x + w.w*qb.z;
    float z1 = w.x*qa.y + w.y*qa.w + w.z*qb.y + w.w*qb.w;
    atomicAdd(out2 + (size_t)s*2 + 0, z0);
    atomicAdd(out2 + (size_t)s*2 + 1, z1);
}

__global__ __launch_bounds__(256) void logsoftmax_k(
    const float* __restrict__ out2, float* __restrict__ out, int N)
{
    int n = blockIdx.x * 256 + threadIdx.x;
    if (n >= N) return;
    float o0 = out2[(size_t)n*2], o1 = out2[(size_t)n*2 + 1];
    float m = fmaxf(o0, o1);
    float lse = m + logf(expf(o0 - m) + expf(o1 - m));
    out[(size_t)n*2]     = o0 - lse;
    out[(size_t)n*2 + 1] = o1 - lse;
}

extern "C" void kernel_launch(void* const* d_in, const int* in_sizes, int n_in,
                              void* d_out, int out_size, void* d_ws, size_t ws_size,
                              hipStream_t stream)
{
    const float* x     = (const float*)d_in[0];
    const int*   ei    = (const int*)d_in[1];
    const float* attr  = (const float*)d_in[2];
    const float* cut   = (const float*)d_in[3];
    const float* cw1   = (const float*)d_in[4];
    const float* cb1   = (const float*)d_in[5];
    const float* f1w1  = (const float*)d_in[6];
    const float* f1b1  = (const float*)d_in[7];
    const float* f2w1  = (const float*)d_in[8];
    const float* f2b1  = (const float*)d_in[9];
    const float* th1   = (const float*)d_in[10];
    const float* rt1   = (const float*)d_in[11];
    const float* bs1   = (const float*)d_in[12];
    const float* cw2   = (const float*)d_in[13];
    const float* cb2   = (const float*)d_in[14];
    const float* f1w2  = (const float*)d_in[15];
    const float* f1b2  = (const float*)d_in[16];
    const float* f2w2  = (const float*)d_in[17];
    const float* f2b2  = (const float*)d_in[18];
    const float* th2   = (const float*)d_in[19];
    const float* rt2   = (const float*)d_in[20];
    const float* bs2   = (const float*)d_in[21];

    const int N = in_sizes[0] / 64;
    const int E = in_sizes[1] / 2;
    const int M = 2 * E;
    const int NB = (N + 127) >> SHIFT;

    // ---- workspace layout (words) ----
    size_t W = 0;
    float* ws = (float*)d_ws;
    float* wedge1 = ws + W;            W += (size_t)E * 4;
    float* wedge2 = ws + W;            W += (size_t)E * 4;
    uint2* tmp    = (uint2*)(ws + W);  W += (size_t)NB * BCAP * 2;  // padded buckets
    int* off      = (int*)(ws + W);    W += N;
    int* deg      = (int*)(ws + W);    W += N;
    int* bcur     = (int*)(ws + W);    W += NB;
    W = (W + 31) & ~(size_t)31;
    __half* x_h = (__half*)(ws + W);               // 32N words
    float*  h1  = ws + W + (size_t)N * 32;         // 20N
    float*  P2  = ws + W + (size_t)N * 52;         // 8N
    float*  o2  = ws + W + (size_t)N * 60;         // 2N
    size_t need_new = W + (size_t)N * 62;

    bool okNew = (NB <= NB_MAX) && (E <= 0x3FFFFF) && (ws_size / 4 >= need_new);

    if (okNew) {
        filter_kernel<<<(E + 255) / 256, 256, 0, stream>>>(
            attr, cut, cw1, cb1, f1w1, f1b1, f2w1, f2b1,
            cw2, cb2, f1w2, f1b2, f2w2, f2b2, wedge1, wedge2, E);
        init_bcur_kernel<<<(NB + 255) / 256, 256, 0, stream>>>(bcur, NB);
        passB_kernel<<<(M + CHUNKB - 1) / CHUNKB, 256, 0, stream>>>(
            ei, bcur, tmp, E, M, NB);
        passC_kernel<<<NB, 256, 0, stream>>>(tmp, bcur, off, deg, N);
        node_prep1b<<<(N * 8 + 255) / 256, 256, 0, stream>>>(x, rt1, bs1, h1, x_h, N);
        gather1_fused<<<(N * 8 + 255) / 256, 256, 0, stream>>>(
            off, deg, tmp, (const float4*)wedge1, x_h, h1,
            th1, rt2, th2, bs2, o2, P2, N);
        gather2_lsm_kernel<<<(N * 8 + 255) / 256, 256, 0, stream>>>(
            off, deg, tmp, (const float4*)wedge2, (const float4*)P2, o2,
            (float*)d_out, N);
    } else {
        // Fallback: atomic scatter (correct but slow). Independent layout.
        float* fw1 = ws;                           // 4E
        float* fw2 = fw1 + (size_t)E * 4;          // 4E
        float* P1  = fw2 + (size_t)E * 4;          // 80N
        float* fh1 = P1  + (size_t)N * 80;         // 20N
        float* fP2 = fh1 + (size_t)N * 20;         // 8N
        float* fo2 = fP2 + (size_t)N * 8;          // 2N
        filter_kernel<<<(E + 255) / 256, 256, 0, stream>>>(
            attr, cut, cw1, cb1, f1w1, f1b1, f2w1, f2b1,
            cw2, cb2, f1w2, f1b2, f2w2, f2b2, fw1, fw2, E);
        node_prep1<<<(N + 7) / 8, 256, 0, stream>>>(x, rt1, th1, bs1, fh1, P1, N);
        edge_scatter1<<<(E + 255) / 256, 256, 0, stream>>>(
            ei, (const float4*)fw1, (const float4*)P1, fh1, E);
        node_prep2<<<(N + 255) / 256, 256, 0, stream>>>(fh1, rt2, th2, bs2, fo2, fP2, N);
        edge_scatter2<<<(E + 255) / 256, 256, 0, stream>>>(
            ei, (const float4*)fw2, (const float4*)fP2, fo2, E);
        logsoftmax_k<<<(N + 255) / 256, 256, 0, stream>>>(fo2, (float*)d_out, N);
    }
}